// Round 6
// baseline (1094.787 us; speedup 1.0000x reference)
//
#include <hip/hip_runtime.h>

#define CH 16
#define HID 128
#define NB 8
#define NH 256
#define NW 256
#define NPX (NB*NH*NW)
#define NSTEP 10
#define GPW 8
#define KPW 2
#define SLAB 1280
#define NPART 64
#define PSTR 1088
#define POFF (NPART*PSTR)          /* 69632 */
#define STEPSTATS (POFF + 640)     /* 70272 */

typedef __attribute__((ext_vector_type(8))) short short8v;
typedef __attribute__((ext_vector_type(4))) float f32x4;

__device__ __forceinline__ int refl(int i, int n){
    if (i < 0) i = -i;
    if (i >= n) i = 2*n - 2 - i;
    return i;
}

__device__ __forceinline__ unsigned short f2bf(float x){
    unsigned int u = __float_as_uint(x);
    u += 0x7FFFu + ((u >> 16) & 1u);
    return (unsigned short)(u >> 16);
}
__device__ __forceinline__ float bf2f(unsigned short h){
    return __uint_as_float(((unsigned int)h) << 16);
}
__device__ __forceinline__ unsigned int cvtpk(float lo, float hi){
    unsigned int r;
    asm("v_cvt_pk_bf16_f32 %0, %1, %2" : "=v"(r) : "v"(lo), "v"(hi));
    return r;
}

// wp[tap][c]; b0 frags: [n][lane][i] -> W0 tiles (lane&15 = hidden-within-16, k = cat channel)
__global__ void k_repack(const float* __restrict__ cw, const float* __restrict__ w0,
                         float* __restrict__ wp,
                         unsigned short* __restrict__ b0h, unsigned short* __restrict__ b0l){
    int t = blockIdx.x*256 + threadIdx.x;
    if (t < 49*16){ int tap = t >> 4, c = t & 15; wp[tap*16 + c] = cw[c*49 + tap]; }
    if (t < 4096){
        int n = t >> 9, l = (t >> 3) & 63, i = t & 7;
        int o = 16*n + (l & 15), k = ((l >> 4) << 3) + i;
        float v = w0[o*32 + k];
        unsigned short hi = f2bf(v);
        b0h[t] = hi;
        b0l[t] = f2bf(v - bf2f(hi));
    }
}

__global__ void k_zero(float* __restrict__ p, int n){
    int t = blockIdx.x*256 + threadIdx.x;
    if (t < n) p[t] = 0.f;
}

// ---- conv: 32x32 px tile, 4-ch group, thread = 2x2 quad, even/odd column planes ----
struct Row { float4 e[4]; float4 o[4]; };

__device__ __forceinline__ void fma4(float4& a, float4 w, float4 v){
    a.x += w.x*v.x; a.y += w.y*v.y; a.z += w.z*v.z; a.w += w.w*v.w;
}
__device__ __forceinline__ void ldrow(Row& r, const float4* L, int row, int tx){
    #pragma unroll
    for (int k=0;k<4;++k){
        r.e[k] = L[(row*2+0)*20 + tx + k];
        r.o[k] = L[(row*2+1)*20 + tx + k];
    }
}

__global__ __launch_bounds__(256,3)
void k_conv(const float* __restrict__ st, const float* __restrict__ wp,
            const float* __restrict__ cb, float* __restrict__ dout){
    __shared__ float4 tile4[38*2*20];
    __shared__ float4 cw4s[49];
    const int b = blockIdx.z >> 2, cg = blockIdx.z & 3;
    const int y0 = blockIdx.y*32, x0 = blockIdx.x*32;
    const int t = threadIdx.x;
    const int tx = t & 15, ty = t >> 4;

    if (t < 49) cw4s[t] = *(const float4*)&wp[t*16 + cg*4];
    for (int i = t; i < 38*38; i += 256){
        int py = i / 38, px = i - py*38;
        int gy = refl(y0 + py - 3, NH);
        int gx = refl(x0 + px - 3, NW);
        float4 v = *(const float4*)&st[(((size_t)b*NH + gy)*NW + gx)*CH + cg*4];
        tile4[(py*2 + (px&1))*20 + (px>>1)] = v;
    }
    __syncthreads();

    const float4* L = tile4;
    float4 bias = *(const float4*)&cb[cg*4];
    float4 a00 = bias, a01 = bias, a10 = bias, a11 = bias;
    Row A, B;
    ldrow(A, L, 2*ty,   tx);
    ldrow(B, L, 2*ty+1, tx);

#define CSTEP(dy, RA, RB, LOADNEXT, NR) \
    { \
        _Pragma("unroll") \
        for (int dx = 0; dx < 7; ++dx){ \
            float4 w4 = cw4s[(dy)*7 + dx]; \
            float4 v00 = ((dx)&1)   ? RA.o[(dx)>>1]   : RA.e[(dx)>>1]; \
            float4 v01 = ((dx+1)&1) ? RA.o[(dx+1)>>1] : RA.e[(dx+1)>>1]; \
            float4 v10 = ((dx)&1)   ? RB.o[(dx)>>1]   : RB.e[(dx)>>1]; \
            float4 v11 = ((dx+1)&1) ? RB.o[(dx+1)>>1] : RB.e[(dx+1)>>1]; \
            fma4(a00,w4,v00); fma4(a01,w4,v01); fma4(a10,w4,v10); fma4(a11,w4,v11); \
        } \
        if (LOADNEXT) ldrow(RA, L, NR, tx); \
    }

    CSTEP(0, A, B, 1, 2*ty+2)
    CSTEP(1, B, A, 1, 2*ty+3)
    CSTEP(2, A, B, 1, 2*ty+4)
    CSTEP(3, B, A, 1, 2*ty+5)
    CSTEP(4, A, B, 1, 2*ty+6)
    CSTEP(5, B, A, 1, 2*ty+7)
    CSTEP(6, A, B, 0, 0)
#undef CSTEP

    const size_t pr = ((size_t)b*NH + (size_t)(y0 + 2*ty))*NW + (x0 + 2*tx);
    *(float4*)&dout[(pr)*CH + cg*4]        = a00;
    *(float4*)&dout[(pr+1)*CH + cg*4]      = a01;
    *(float4*)&dout[(pr+NW)*CH + cg*4]     = a10;
    *(float4*)&dout[(pr+NW+1)*CH + cg*4]   = a11;
}

// MFMA second moments into 64 partial buffers (atomic chain 16 deep, no mirror writes).
// All global loads issued upfront (8 float4/wave in flight) for latency hiding.
__global__ __launch_bounds__(512)
void k_stats(const float* __restrict__ st, const float* __restrict__ dv,
             float* __restrict__ S){
    __shared__ float lds[8*SLAB];
    const int t = threadIdx.x, lane = t & 63, w = t >> 6;
    const int lo = lane & 15, hi = lane >> 4;
    float* slab = &lds[w*SLAB];
    const int gw = blockIdx.x*8 + w;           // 0..8191

    short8v ones;
    {
        short ov = (lo == 0) ? (short)0x3F80 : (short)0;
        #pragma unroll
        for (int i=0;i<8;++i) ones[i] = ov;
    }
    f32x4 a00 = (f32x4){0.f,0.f,0.f,0.f};
    f32x4 a01 = a00, a11 = a00, s0 = a00, s1 = a00;

    const int lp = lane >> 3, lq = lane & 7;
    const float* lbase = (lq < 4) ? st : dv;
    const int lch = (lq & 3) * 4;
    const size_t p0 = (size_t)gw * (KPW*32);

    float4 v[KPW][4];
    #pragma unroll
    for (int j=0;j<KPW;++j)
        #pragma unroll
        for (int j2=0;j2<4;++j2)
            v[j][j2] = *(const float4*)&lbase[(p0 + j*32 + lp + 8*j2)*CH + lch];

    #pragma unroll
    for (int j=0;j<KPW;++j){
        #pragma unroll
        for (int j2=0;j2<4;++j2){
            int p = lp + 8*j2;
            *(float2*)&slab[p*34 + lq*4]     = make_float2(v[j][j2].x, v[j][j2].y);
            *(float2*)&slab[p*34 + lq*4 + 2] = make_float2(v[j][j2].z, v[j][j2].w);
        }
        short8v r0h, r0l, r1h, r1l;
        #pragma unroll
        for (int ct=0;ct<2;++ct){
            #pragma unroll
            for (int i=0;i<8;++i){
                float f = slab[(hi*8+i)*34 + ct*16 + lo];
                unsigned int u = __float_as_uint(f);
                unsigned short ah = (unsigned short)(u >> 16);
                float r = f - __uint_as_float(u & 0xFFFF0000u);
                unsigned short al = (unsigned short)(__float_as_uint(r) >> 16);
                if (ct==0){ r0h[i]=(short)ah; r0l[i]=(short)al; }
                else      { r1h[i]=(short)ah; r1l[i]=(short)al; }
            }
        }
        s0 = __builtin_amdgcn_mfma_f32_16x16x32_bf16(ones, r0h, s0, 0,0,0);
        s0 = __builtin_amdgcn_mfma_f32_16x16x32_bf16(ones, r0l, s0, 0,0,0);
        s1 = __builtin_amdgcn_mfma_f32_16x16x32_bf16(ones, r1h, s1, 0,0,0);
        s1 = __builtin_amdgcn_mfma_f32_16x16x32_bf16(ones, r1l, s1, 0,0,0);
        a00 = __builtin_amdgcn_mfma_f32_16x16x32_bf16(r0h, r0h, a00, 0,0,0);
        a00 = __builtin_amdgcn_mfma_f32_16x16x32_bf16(r0l, r0h, a00, 0,0,0);
        a00 = __builtin_amdgcn_mfma_f32_16x16x32_bf16(r0h, r0l, a00, 0,0,0);
        a11 = __builtin_amdgcn_mfma_f32_16x16x32_bf16(r1h, r1h, a11, 0,0,0);
        a11 = __builtin_amdgcn_mfma_f32_16x16x32_bf16(r1l, r1h, a11, 0,0,0);
        a11 = __builtin_amdgcn_mfma_f32_16x16x32_bf16(r1h, r1l, a11, 0,0,0);
        a01 = __builtin_amdgcn_mfma_f32_16x16x32_bf16(r0h, r1h, a01, 0,0,0);
        a01 = __builtin_amdgcn_mfma_f32_16x16x32_bf16(r0l, r1h, a01, 0,0,0);
        a01 = __builtin_amdgcn_mfma_f32_16x16x32_bf16(r0h, r1l, a01, 0,0,0);
    }

    // per-thread partials land inside the thread's own wave slab (64*20 = SLAB)
    float* red = lds;
    #pragma unroll
    for (int k=0;k<4;++k){
        red[t*20 + k]      = a00[k];
        red[t*20 + 4 + k]  = a01[k];
        red[t*20 + 8 + k]  = a11[k];
        red[t*20 + 12 + k] = s0[k];
        red[t*20 + 16 + k] = s1[k];
    }
    __syncthreads();
    if (w == 0){
        float tmp[20];
        #pragma unroll
        for (int k=0;k<20;++k){
            float s = 0.f;
            #pragma unroll
            for (int ww=0;ww<8;++ww) s += red[(lane + 64*ww)*20 + k];
            tmp[k] = s;
        }
        float* part = S + (size_t)(blockIdx.x & (NPART-1))*PSTR;
        #pragma unroll
        for (int r=0;r<4;++r){
            atomicAdd(&part[(hi*4+r)*32 + lo],        tmp[r]);
            atomicAdd(&part[(hi*4+r)*32 + 16 + lo],   tmp[4+r]);   // upper-right only
            atomicAdd(&part[(16+hi*4+r)*32 + 16+lo],  tmp[8+r]);
        }
        if (hi == 0){
            atomicAdd(&part[1024 + lo],      tmp[12]);
            atomicAdd(&part[1024 + 16 + lo], tmp[16]);
        }
    }
}

// Sum 64 partials -> Ssm (LDS), symmetrize a01 on read, then BN fold:
// relu(sc*x+sh) = sc*relu(x + sh/sc) since sc>0. Emits shb (MFMA C-init) and
// f1s frags = f1 * sc (bf16, out-ch 0 zeroed).
__global__ void k_finalize(const float* __restrict__ Sin,
                           const float* __restrict__ w0, const float* __restrict__ b0,
                           const float* __restrict__ gam, const float* __restrict__ bet,
                           const float* __restrict__ f1, float* __restrict__ Sout){
    __shared__ float Ssm[1056];
    const int t = threadIdx.x;
    for (int e = t; e < 1056; e += 512){
        float s = 0.f;
        #pragma unroll 4
        for (int p = 0; p < NPART; ++p) s += Sin[(size_t)p*PSTR + e];
        Ssm[e] = s;
    }
    __syncthreads();
    if (t < 128){
        const int o = t;
        const float inv = 1.f / (float)NPX;
        float w[32];
        #pragma unroll
        for (int c=0;c<32;++c) w[c] = w0[o*32+c];
        float m1 = 0.f;
        #pragma unroll
        for (int c=0;c<32;++c) m1 += w[c]*Ssm[1024+c];
        m1 *= inv;
        float q = 0.f;
        #pragma unroll
        for (int i=0;i<32;++i){
            float ti = 0.f;
            #pragma unroll
            for (int j=0;j<32;++j){
                float sv = (i >= 16 && j < 16) ? Ssm[j*32+i] : Ssm[i*32+j];
                ti += sv*w[j];
            }
            q += w[i]*ti;
        }
        q *= inv;
        float var = q - m1*m1;
        float rstd = rsqrtf(var + 1e-5f);
        float mean = m1 + b0[o];
        float scale = rstd * gam[o];
        Sout[POFF + o] = bet[o]/scale + b0[o] - mean;    // shb
        unsigned short* f1sh = (unsigned short*)(Sout + POFF + 128);
        const int base = (o>>5)*512 + ((o>>3)&3)*128 + (o&7);
        f1sh[base] = 0;                                   // out-ch 0 pad
        #pragma unroll
        for (int c=1;c<16;++c)
            f1sh[base + c*8] = f2bf(f1[(c-1)*HID + o] * scale);
    }
}

// MFMA update, swapped operands: acc = shb + W0*cat (col=pixel,row=hidden) ->
// relu -> bf16-pack -> LDS -> GEMM2 frag read -> delta (col=pixel,row=channel) -> residual
__global__ __launch_bounds__(256)
void k_update(const float* __restrict__ st, const float* __restrict__ dv,
              const int* __restrict__ msk,
              const unsigned short* __restrict__ gb0h, const unsigned short* __restrict__ gb0l,
              const float* __restrict__ Sstep, float* __restrict__ out){
    __shared__ __align__(16) unsigned int hls[4*16*68];
    const int lane = threadIdx.x & 63, w = threadIdx.x >> 6;
    const int lo16 = lane & 15, qw = lane >> 4;
    unsigned int* hb = &hls[w*16*68];

    const short8v* p0h = (const short8v*)gb0h;
    const short8v* p0l = (const short8v*)gb0l;
    const short8v* p1h = (const short8v*)(Sstep + POFF + 128);
    short8v B0h[8], B0l[8], B1h[4];
    #pragma unroll
    for (int n=0;n<8;++n){ B0h[n] = p0h[n*64 + lane]; B0l[n] = p0l[n*64 + lane]; }
    #pragma unroll
    for (int tt=0;tt<4;++tt) B1h[tt] = p1h[tt*64 + lane];
    const float* shb = Sstep + POFF;
    float4 shbv[8];
    #pragma unroll
    for (int n=0;n<8;++n) shbv[n] = *(const float4*)&shb[16*n + 4*qw];

    const int gw = blockIdx.x*4 + w;
    const float* abase = (qw < 2) ? st : dv;
    const int choff = (qw & 1)*8;

    for (int gi = 0; gi < GPW; ++gi){
        const size_t pg0 = ((size_t)gw*GPW + gi)*16;
        // cat B-fragment: lane = pixel (lo16), k = channel (qw*8+i); truncation hi/lo split
        const float* ap = abase + (pg0 + lo16)*CH + choff;
        float4 v0 = *(const float4*)ap;
        float4 v1 = *(const float4*)(ap + 4);
        float av[8] = {v0.x,v0.y,v0.z,v0.w,v1.x,v1.y,v1.z,v1.w};
        short8v ah, al;
        #pragma unroll
        for (int i=0;i<8;++i){
            unsigned int u = __float_as_uint(av[i]);
            ah[i] = (short)(unsigned short)(u >> 16);
            float r = av[i] - __uint_as_float(u & 0xFFFF0000u);
            al[i] = (short)(unsigned short)(__float_as_uint(r) >> 16);
        }
        f32x4 acc[8];
        #pragma unroll
        for (int n=0;n<8;++n)
            acc[n] = (f32x4){shbv[n].x, shbv[n].y, shbv[n].z, shbv[n].w};
        #pragma unroll
        for (int n=0;n<8;++n){
            acc[n] = __builtin_amdgcn_mfma_f32_16x16x32_bf16(B0h[n], ah, acc[n], 0,0,0);
            acc[n] = __builtin_amdgcn_mfma_f32_16x16x32_bf16(B0h[n], al, acc[n], 0,0,0);
            acc[n] = __builtin_amdgcn_mfma_f32_16x16x32_bf16(B0l[n], ah, acc[n], 0,0,0);
        }
        // relu + bf16 pack -> LDS (per-wave region; same-wave RAW ordered by waitcnt)
        #pragma unroll
        for (int n=0;n<8;++n){
            float h0 = fmaxf(acc[n][0], 0.f), h1 = fmaxf(acc[n][1], 0.f);
            float h2 = fmaxf(acc[n][2], 0.f), h3 = fmaxf(acc[n][3], 0.f);
            unsigned int wa = cvtpk(h0, h1), wb = cvtpk(h2, h3);
            *(uint2*)&hb[lo16*68 + 8*n + 2*qw] = make_uint2(wa, wb);
        }
        // GEMM2: A = f1s (m = out-ch), B = h (lane = pixel, k = hidden 32tt+8qw+i)
        f32x4 dacc = (f32x4){0.f,0.f,0.f,0.f};
        #pragma unroll
        for (int tt=0;tt<4;++tt){
            short8v ah2 = *(const short8v*)&hb[lo16*68 + 16*tt + 4*qw];
            dacc = __builtin_amdgcn_mfma_f32_16x16x32_bf16(B1h[tt], ah2, dacc, 0,0,0);
        }
        // epilogue: lane holds delta for channels 4qw..4qw+3 of pixel pg0+lo16
        const size_t p = pg0 + lo16;
        float4 stv = *(const float4*)&st[p*CH + 4*qw];
        const float m = (float)msk[p];
        float4 ov;
        ov.x = stv.x + dacc[0]*m;
        ov.y = stv.y + dacc[1]*m;
        ov.z = stv.z + dacc[2]*m;
        ov.w = stv.w + dacc[3]*m;
        *(float4*)&out[p*CH + 4*qw] = ov;
    }
}

extern "C" void kernel_launch(void* const* d_in, const int* in_sizes, int n_in,
                              void* d_out, int out_size, void* d_ws, size_t ws_size,
                              hipStream_t stream){
    const float* x   = (const float*)d_in[0];
    const int*   mk  = (const int*)d_in[1];
    const float* cw  = (const float*)d_in[2];
    const float* cb  = (const float*)d_in[3];
    const float* w0  = (const float*)d_in[4];
    const float* b0  = (const float*)d_in[5];
    const float* f1  = (const float*)d_in[6];
    const float* gam = (const float*)d_in[7];
    const float* bet = (const float*)d_in[8];

    float* ws    = (float*)d_ws;
    float* dbuf  = ws;                          // NPX*CH
    float* sbuf  = ws + (size_t)NPX*CH;         // NPX*CH
    float* stats = ws + (size_t)2*NPX*CH;       // NSTEP*STEPSTATS
    float* wp    = stats + (size_t)NSTEP*STEPSTATS; // 800
    unsigned short* b0h = (unsigned short*)(wp + 800);
    unsigned short* b0l = b0h + 4096;

    k_repack<<<16,256,0,stream>>>(cw, w0, wp, b0h, b0l);
    k_zero<<<(NSTEP*STEPSTATS+255)/256,256,0,stream>>>(stats, NSTEP*STEPSTATS);

    const float* cur = x;
    float* outp = (float*)d_out;
    for (int s=0;s<NSTEP;++s){
        float* S = stats + (size_t)s*STEPSTATS;
        float* nxt = (s & 1) ? outp : sbuf;     // s=9 lands in d_out
        k_conv<<<dim3(NW/32,NH/32,NB*4),256,0,stream>>>(cur, wp, cb, dbuf);
        k_stats<<<1024,512,0,stream>>>(cur, dbuf, S);
        k_finalize<<<1,512,0,stream>>>(S, w0, b0, gam, bet, f1, S);
        k_update<<<NPX/16/4/GPW,256,0,stream>>>(cur, dbuf, mk + (size_t)s*NPX,
                                                b0h, b0l, S, nxt);
        cur = nxt;
    }
}